// Round 6
// baseline (3626.245 us; speedup 1.0000x reference)
//
#include <hip/hip_runtime.h>
#include <math.h>

#define B_SZ 4096
#define T_SZ 80
#define V_SZ 80
#define E_SZ 8
#define H_SZ 256
#define G4   1024   // 4*H
#define S72  72     // LDS row stride in shorts (144B: 2-way-free banks, pads LDS to force 2 blocks/CU)

typedef __attribute__((ext_vector_type(8))) short short8;
typedef __attribute__((ext_vector_type(4))) float f32x4;

__device__ __forceinline__ float sigm(float x) {
    return 1.f / (1.f + __expf(-x));
}
__device__ __forceinline__ float tanhfast(float x) {
    x = fminf(fmaxf(x, -15.f), 15.f);
    float t = __expf(-2.f * x);
    return (1.f - t) / (1.f + t);
}
__device__ __forceinline__ ushort f2bf(float f) {   // RNE f32->bf16
    unsigned u = __float_as_uint(f);
    u = (u + 0x7fffu + ((u >> 16) & 1u)) >> 16;
    return (ushort)u;
}

// 16B load that bypasses L1+L2 (agent scope) -> always fresh from L3
__device__ __forceinline__ short8 bp16(const ushort* p) {
    union { unsigned long long u[2]; short8 v; } r;
    r.u[0] = __hip_atomic_load((const unsigned long long*)p,
                               __ATOMIC_RELAXED, __HIP_MEMORY_SCOPE_AGENT);
    r.u[1] = __hip_atomic_load((const unsigned long long*)p + 1,
                               __ATOMIC_RELAXED, __HIP_MEMORY_SCOPE_AGENT);
    return r.v;
}

__device__ __forceinline__ void spin_ge(const int* f, int target) {
    int n = 0;
    while (__hip_atomic_load(f, __ATOMIC_RELAXED, __HIP_MEMORY_SCOPE_AGENT) < target) {
        __builtin_amdgcn_s_sleep(2);
        if (++n > (1 << 20)) break;   // bail-out: wrong answer beats a hang
    }
}

// G1[v][col] = b1[col] + sum_e emb[v][e] * W1[e][col]
__global__ __launch_bounds__(256) void g1_kernel(const float* __restrict__ emb,
                                                 const float* __restrict__ W1,
                                                 const float* __restrict__ b1,
                                                 float* __restrict__ G1) {
    int idx = blockIdx.x * 256 + threadIdx.x;
    if (idx >= V_SZ * G4) return;
    int v = idx >> 10, col = idx & 1023;
    float g = b1[col];
#pragma unroll
    for (int e = 0; e < E_SZ; e++)
        g += emb[v * E_SZ + e] * W1[e * G4 + col];
    G1[idx] = g;
}

// Wt[n][k] = bf16(src[(k0+k)*1024 + n])
__global__ __launch_bounds__(256) void wtrans(const float* __restrict__ src, int k0,
                                              int Kshift, ushort* __restrict__ out) {
    const int K = 1 << Kshift;
    int idx = blockIdx.x * 256 + threadIdx.x;
    int n = idx >> Kshift, k = idx & (K - 1);
    out[idx] = f2bf(src[(size_t)(k0 + k) * G4 + n]);
}

// WdT[v][h] = bf16(Wd[h*V + v])
__global__ __launch_bounds__(256) void wdtrans(const float* __restrict__ src,
                                               ushort* __restrict__ out) {
    int idx = blockIdx.x * 256 + threadIdx.x;
    if (idx >= V_SZ * H_SZ) return;
    int v = idx >> 8, h = idx & 255;
    out[idx] = f2bf(src[h * V_SZ + v]);
}

// Persistent 2-layer LSTM. Grid (8 h-blocks, 32 m-groups, 2 layers) = 512 blocks.
// LDS 72KB/block -> exactly 2 blocks/CU, all co-resident (pigeonhole).
// Block owns a fixed 128-row x 32-hcol tile for all 80 steps; c stays in VGPRs.
// Group sync: per-(t,layer) flags counted to 8; h flushed via buffer_wbl2 sc1;
// h reads bypass L1/L2 (agent-scope loads) so ping-pong reuse is stale-safe.
__global__ __launch_bounds__(256) void lstm_persist(
    const int*   __restrict__ feat,
    const float* __restrict__ G1,
    const float* __restrict__ b2,
    ushort* h1a, ushort* h1bb, ushort* h2a, ushort* h2bb,
    const ushort* __restrict__ W1t, const ushort* __restrict__ W2t,
    int* flags) {

    __shared__ __align__(16) ushort As[2][128 * S72];
    __shared__ __align__(16) ushort Ws[2][128 * S72];

    const int z  = blockIdx.z;          // 0: layer1, 1: layer2
    const int g  = blockIdx.y;          // m-group
    const int m0 = g * 128;
    const int h0 = blockIdx.x * 32;
    const int tid = threadIdx.x;
    const int w = tid >> 6, l = tid & 63;
    const int l15 = l & 15, l4 = l >> 4;

    const int K = z ? 512 : 256;
    const ushort* __restrict__ Wt = z ? W2t : W1t;

    // staging geometry: thread stages 16B chunks (row0,c40) and (row1,c40)
    const int row0 = tid >> 2, c40 = tid & 3;
    const int row1 = row0 + 64;
    const int ncol0 = (row0 >> 5) * 256 + h0 + (row0 & 31);
    const int ncol1 = (row1 >> 5) * 256 + h0 + (row1 & 31);
    const size_t wb0 = (size_t)ncol0 * K + c40 * 8;
    const size_t wb1 = (size_t)ncol1 * K + c40 * 8;
    const int lA0 = row0 * S72 + c40 * 8, lA1 = row1 * S72 + c40 * 8;

    // fragment offsets
    const int aoff0 = (w * 32 + l15) * S72 + l4 * 8;
    const int aoff1 = aoff0 + 16 * S72;
    const int boff  = l15 * S72 + l4 * 8;

    ushort* h1buf[2] = {h1a, h1bb};
    ushort* h2buf[2] = {h2a, h2bb};

    float creg[16];
#pragma unroll
    for (int i = 0; i < 16; i++) creg[i] = 0.f;

    const f32x4 zero4 = {0.f, 0.f, 0.f, 0.f};

    for (int t = 0; t < T_SZ; t++) {
        // ---- dependency wait (tid0 spins, block gated by barrier)
        if (tid == 0) {
            if (!z) {
                if (t >= 1) spin_ge(&flags[((t - 1) * 2 + 0) * 32 + g], 8);  // h1[t-1] data
                if (t >= 2) spin_ge(&flags[((t - 2) * 2 + 1) * 32 + g], 8);  // h1 buffer anti-dep
            } else {
                spin_ge(&flags[(t * 2 + 0) * 32 + g], 8);                    // h1[t] data
                if (t >= 1) spin_ge(&flags[((t - 1) * 2 + 1) * 32 + g], 8);  // h2[t-1] data+anti
            }
        }
        __syncthreads();

        const int Kend = z ? (t ? 512 : 256) : (t ? 256 : 0);
        const ushort* A1 = z ? h1buf[t & 1] : h1buf[(t + 1) & 1];  // z0: h1[t-1]; z1: h1[t]
        const ushort* A2 = h2buf[(t + 1) & 1];                     // z1: h2[t-1]

        f32x4 acc[2][8];
#pragma unroll
        for (int fg = 0; fg < 2; fg++)
#pragma unroll
            for (int cf = 0; cf < 8; cf++) acc[fg][cf] = zero4;

        auto loadTile = [&](int kt, short8& a0, short8& a1, short8& w0, short8& w1) {
            const ushort* Asrc; int kl;
            if (!z || kt < 256) { Asrc = A1; kl = kt; }
            else                { Asrc = A2; kl = kt - 256; }
            a0 = bp16(Asrc + (size_t)(m0 + row0) * H_SZ + kl + c40 * 8);
            a1 = bp16(Asrc + (size_t)(m0 + row1) * H_SZ + kl + c40 * 8);
            w0 = *(const short8*)(Wt + wb0 + kt);
            w1 = *(const short8*)(Wt + wb1 + kt);
        };

        short8 ga0, ga1, gw0, gw1;
        if (Kend > 0) {
            loadTile(0, ga0, ga1, gw0, gw1);
            *(short8*)(As[0] + lA0) = ga0;
            *(short8*)(As[0] + lA1) = ga1;
            *(short8*)(Ws[0] + lA0) = gw0;
            *(short8*)(Ws[0] + lA1) = gw1;
            if (Kend > 32) loadTile(32, ga0, ga1, gw0, gw1);
            __syncthreads();
        }

        int cur = 0;
        for (int kt = 0; kt < Kend; kt += 32) {
            short8 a0 = *(const short8*)(As[cur] + aoff0);
            short8 a1 = *(const short8*)(As[cur] + aoff1);
            short8 bq[8];
#pragma unroll
            for (int cf = 0; cf < 8; cf++)
                bq[cf] = *(const short8*)(Ws[cur] + boff + cf * (16 * S72));

            __builtin_amdgcn_s_setprio(1);
#pragma unroll
            for (int cf = 0; cf < 8; cf++) {
                acc[0][cf] = __builtin_amdgcn_mfma_f32_16x16x32_bf16(a0, bq[cf], acc[0][cf], 0, 0, 0);
                acc[1][cf] = __builtin_amdgcn_mfma_f32_16x16x32_bf16(a1, bq[cf], acc[1][cf], 0, 0, 0);
            }
            __builtin_amdgcn_s_setprio(0);

            if (kt + 32 < Kend) {
                *(short8*)(As[cur ^ 1] + lA0) = ga0;
                *(short8*)(As[cur ^ 1] + lA1) = ga1;
                *(short8*)(Ws[cur ^ 1] + lA0) = gw0;
                *(short8*)(Ws[cur ^ 1] + lA1) = gw1;
                if (kt + 64 < Kend) loadTile(kt + 64, ga0, ga1, gw0, gw1);
            }
            __syncthreads();
            cur ^= 1;
        }

        // ---- fused LSTM cell epilogue (c in registers). D: row=(l>>4)*4+r, col=l&15.
        ushort* hout = z ? h2buf[t & 1] : h1buf[t & 1];
        const bool cz = (t == 0);

#pragma unroll
        for (int fg = 0; fg < 2; fg++) {
#pragma unroll
            for (int r = 0; r < 4; r++) {
                const int grow = m0 + w * 32 + fg * 16 + l4 * 4 + r;
                const float* gb = z ? b2 : (G1 + (size_t)feat[(size_t)grow * T_SZ + t] * G4);
#pragma unroll
                for (int h16 = 0; h16 < 2; h16++) {
                    const int hcol = h0 + h16 * 16 + l15;
                    float gi = acc[fg][0 + h16][r] + gb[hcol];
                    float gj = acc[fg][2 + h16][r] + gb[256 + hcol];
                    float gf = acc[fg][4 + h16][r] + gb[512 + hcol];
                    float go = acc[fg][6 + h16][r] + gb[768 + hcol];
                    const int cidx = (fg * 4 + r) * 2 + h16;
                    float cp = cz ? 0.f : creg[cidx];
                    float cn = cp * sigm(gf + 1.f) + sigm(gi) * tanhfast(gj);
                    float hn = tanhfast(cn) * sigm(go);
                    creg[cidx] = cn;
                    hout[(size_t)grow * H_SZ + hcol] = f2bf(hn);
                }
            }
        }

        __syncthreads();   // all waves' h stores drained to L2 (implicit vmcnt at barrier)
        if (tid == 0) {
            asm volatile("buffer_wbl2 sc1" ::: "memory");       // flush this XCD's L2 -> L3
            asm volatile("s_waitcnt vmcnt(0)" ::: "memory");
            __hip_atomic_fetch_add(&flags[(t * 2 + z) * 32 + g], 1,
                                   __ATOMIC_RELAXED, __HIP_MEMORY_SCOPE_AGENT);
        }
    }
}

// dense+loss via MFMA: wave computes 16 rows x 80 v-cols; shfl softmax.
__global__ __launch_bounds__(256) void dense_loss(const ushort* __restrict__ h2,
                                                  const ushort* __restrict__ WdT,
                                                  const float* __restrict__ bd,
                                                  const int* __restrict__ labels,
                                                  float* __restrict__ out) {
    const int tid = threadIdx.x;
    const int w = tid >> 6, l = tid & 63;
    const int l15 = l & 15, l4 = l >> 4;
    const int m0 = blockIdx.x * 64 + w * 16;

    f32x4 acc[5];
    const f32x4 zero4 = {0.f, 0.f, 0.f, 0.f};
#pragma unroll
    for (int cf = 0; cf < 5; cf++) acc[cf] = zero4;

    for (int kt = 0; kt < 256; kt += 32) {
        short8 a = *(const short8*)(h2 + (size_t)(m0 + l15) * H_SZ + l4 * 8 + kt);
#pragma unroll
        for (int cf = 0; cf < 5; cf++) {
            short8 b = *(const short8*)(WdT + (size_t)(cf * 16 + l15) * H_SZ + l4 * 8 + kt);
            acc[cf] = __builtin_amdgcn_mfma_f32_16x16x32_bf16(a, b, acc[cf], 0, 0, 0);
        }
    }
#pragma unroll
    for (int cf = 0; cf < 5; cf++) {
        float bv = bd[cf * 16 + l15];
#pragma unroll
        for (int r = 0; r < 4; r++) acc[cf][r] += bv;
    }

#pragma unroll
    for (int r = 0; r < 4; r++) {
        const int row = m0 + l4 * 4 + r;
        float mx = acc[0][r];
#pragma unroll
        for (int cf = 1; cf < 5; cf++) mx = fmaxf(mx, acc[cf][r]);
#pragma unroll
        for (int msk = 1; msk < 16; msk <<= 1)
            mx = fmaxf(mx, __shfl_xor(mx, msk, 64));
        float s = 0.f;
#pragma unroll
        for (int cf = 0; cf < 5; cf++) s += __expf(acc[cf][r] - mx);
#pragma unroll
        for (int msk = 1; msk < 16; msk <<= 1)
            s += __shfl_xor(s, msk, 64);
        const int lab = labels[row];
        float pl = 0.f;
#pragma unroll
        for (int cf = 0; cf < 5; cf++)
            pl += (cf * 16 + l15 == lab) ? acc[cf][r] : 0.f;
#pragma unroll
        for (int msk = 1; msk < 16; msk <<= 1)
            pl += __shfl_xor(pl, msk, 64);
        if (l15 == 0)
            atomicAdd(out, (logf(s) + mx - pl) * (1.0f / B_SZ));
    }
}

extern "C" void kernel_launch(void* const* d_in, const int* in_sizes, int n_in,
                              void* d_out, int out_size, void* d_ws, size_t ws_size,
                              hipStream_t stream) {
    const int*   features = (const int*)d_in[0];
    const int*   labels   = (const int*)d_in[1];
    const float* emb      = (const float*)d_in[2];
    const float* W1       = (const float*)d_in[3];
    const float* b1       = (const float*)d_in[4];
    const float* W2       = (const float*)d_in[5];
    const float* b2       = (const float*)d_in[6];
    const float* Wd       = (const float*)d_in[7];
    const float* bd       = (const float*)d_in[8];
    float* out = (float*)d_out;

    char* base = (char*)d_ws;
    float*  G1v = (float*)base;      base += (size_t)V_SZ * G4 * 4;       // 320 KB
    ushort* h1a = (ushort*)base;     base += (size_t)B_SZ * H_SZ * 2;     // 2 MB
    ushort* h1b = (ushort*)base;     base += (size_t)B_SZ * H_SZ * 2;
    ushort* h2a = (ushort*)base;     base += (size_t)B_SZ * H_SZ * 2;
    ushort* h2b = (ushort*)base;     base += (size_t)B_SZ * H_SZ * 2;
    ushort* W1t = (ushort*)base;     base += (size_t)G4 * H_SZ * 2;       // 512 KB
    ushort* W2t = (ushort*)base;     base += (size_t)G4 * 2 * H_SZ * 2;   // 1 MB
    ushort* WdT = (ushort*)base;     base += (size_t)V_SZ * H_SZ * 2;     // 40 KB
    int*    flags = (int*)base;      base += (size_t)T_SZ * 2 * 32 * 4;   // 20 KB

    (void)hipMemsetAsync(d_out, 0, sizeof(float), stream);
    (void)hipMemsetAsync(flags, 0, (size_t)T_SZ * 2 * 32 * 4, stream);

    g1_kernel<<<(V_SZ * G4 + 255) / 256, 256, 0, stream>>>(emb, W1, b1, G1v);
    wtrans<<<(G4 * 256) / 256, 256, 0, stream>>>(W1, E_SZ, 8, W1t);
    wtrans<<<(G4 * 512) / 256, 256, 0, stream>>>(W2, 0, 9, W2t);
    wdtrans<<<(V_SZ * H_SZ + 255) / 256, 256, 0, stream>>>(Wd, WdT);

    lstm_persist<<<dim3(8, 32, 2), 256, 0, stream>>>(
        features, G1v, b2, h1a, h1b, h2a, h2b, W1t, W2t, flags);

    dense_loss<<<B_SZ / 64, 256, 0, stream>>>(h2b[0] ? (const ushort*)((T_SZ - 1) & 1 ? h2b : h2a) : h2a,
                                              WdT, bd, labels, out);
}

// Round 7
// 3249.548 us; speedup vs baseline: 1.1159x; 1.1159x over previous
//
#include <hip/hip_runtime.h>
#include <math.h>

#define B_SZ 4096
#define T_SZ 80
#define V_SZ 80
#define E_SZ 8
#define H_SZ 256
#define G4   1024   // 4*H
#define S40  40     // LDS row stride in shorts (80B, 16B-aligned, measured conflict-free)

typedef __attribute__((ext_vector_type(8))) short short8;
typedef __attribute__((ext_vector_type(4))) float f32x4;
typedef unsigned long long u64;

__device__ __forceinline__ float sigm(float x) {
    return 1.f / (1.f + __expf(-x));
}
__device__ __forceinline__ float tanhfast(float x) {
    x = fminf(fmaxf(x, -15.f), 15.f);
    float t = __expf(-2.f * x);
    return (1.f - t) / (1.f + t);
}
__device__ __forceinline__ ushort f2bf(float f) {   // RNE f32->bf16
    unsigned u = __float_as_uint(f);
    u = (u + 0x7fffu + ((u >> 16) & 1u)) >> 16;
    return (ushort)u;
}

// 16B load bypassing L1+L2 (agent scope) -> reads coherence point (L3)
__device__ __forceinline__ short8 bp16(const ushort* p) {
    union { u64 u[2]; short8 v; } r;
    r.u[0] = __hip_atomic_load((const u64*)p, __ATOMIC_RELAXED, __HIP_MEMORY_SCOPE_AGENT);
    r.u[1] = __hip_atomic_load((const u64*)p + 1, __ATOMIC_RELAXED, __HIP_MEMORY_SCOPE_AGENT);
    return r.v;
}

__device__ __forceinline__ void spin_ge(const int* f, int target) {
    int n = 0;
    while (__hip_atomic_load(f, __ATOMIC_RELAXED, __HIP_MEMORY_SCOPE_AGENT) < target) {
        __builtin_amdgcn_s_sleep(2);
        if (++n > (1 << 21)) break;   // bail-out: wrong answer beats a hang
    }
}

// G1[v][col] = b1[col] + sum_e emb[v][e] * W1[e][col]
__global__ __launch_bounds__(256) void g1_kernel(const float* __restrict__ emb,
                                                 const float* __restrict__ W1,
                                                 const float* __restrict__ b1,
                                                 float* __restrict__ G1) {
    int idx = blockIdx.x * 256 + threadIdx.x;
    if (idx >= V_SZ * G4) return;
    int v = idx >> 10, col = idx & 1023;
    float g = b1[col];
#pragma unroll
    for (int e = 0; e < E_SZ; e++)
        g += emb[v * E_SZ + e] * W1[e * G4 + col];
    G1[idx] = g;
}

// Wt[n][k] = bf16(src[(k0+k)*1024 + n])
__global__ __launch_bounds__(256) void wtrans(const float* __restrict__ src, int k0,
                                              int Kshift, ushort* __restrict__ out) {
    const int K = 1 << Kshift;
    int idx = blockIdx.x * 256 + threadIdx.x;
    int n = idx >> Kshift, k = idx & (K - 1);
    out[idx] = f2bf(src[(size_t)(k0 + k) * G4 + n]);
}

// WdT[v][h] = bf16(Wd[h*V + v])
__global__ __launch_bounds__(256) void wdtrans(const float* __restrict__ src,
                                               ushort* __restrict__ out) {
    int idx = blockIdx.x * 256 + threadIdx.x;
    if (idx >= V_SZ * H_SZ) return;
    int v = idx >> 8, h = idx & 255;
    out[idx] = f2bf(src[h * V_SZ + v]);
}

// Persistent 2-layer LSTM. Grid (8 h-blocks, 32 m-groups, 2 layers) = 512 blocks.
// 56KB LDS/block -> exactly 2 blocks/CU, all co-resident (pigeonhole).
// c-state in VGPRs. h exchanged via write-through stores + L2-bypass loads;
// W/G1 remain L2-cached (no cache maintenance instructions at all).
__global__ __launch_bounds__(256) void lstm_persist(
    const int*   __restrict__ feat,
    const float* __restrict__ G1,
    const float* __restrict__ b2,
    ushort* h1a, ushort* h1bb, ushort* h2a, ushort* h2bb,
    const ushort* __restrict__ W1t, const ushort* __restrict__ W2t,
    int* flags, int padsel) {

    __shared__ __align__(16) ushort As[2][128 * S40];
    __shared__ __align__(16) ushort Ws[2][128 * S40];
    __shared__ ushort fill[8192];   // 16KB pad -> 56KB total -> 2 blocks/CU

    const int z  = blockIdx.z;          // 0: layer1, 1: layer2
    const int g  = blockIdx.y;          // m-group
    const int m0 = g * 128;
    const int h0 = blockIdx.x * 32;
    const int tid = threadIdx.x;
    if (padsel) fill[tid] = 0;          // never true; keeps pad allocated
    const int w = tid >> 6, l = tid & 63;
    const int l15 = l & 15, l4 = l >> 4;

    const int K = z ? 512 : 256;
    const ushort* __restrict__ Wt = z ? W2t : W1t;

    // staging geometry: thread stages 16B chunks (row0,c40) and (row1,c40)
    const int row0 = tid >> 2, c40 = tid & 3;
    const int row1 = row0 + 64;
    const int ncol0 = (row0 >> 5) * 256 + h0 + (row0 & 31);
    const int ncol1 = (row1 >> 5) * 256 + h0 + (row1 & 31);
    const size_t wb0 = (size_t)ncol0 * K + c40 * 8;
    const size_t wb1 = (size_t)ncol1 * K + c40 * 8;
    const int lA0 = row0 * S40 + c40 * 8, lA1 = row1 * S40 + c40 * 8;

    // fragment offsets
    const int aoff0 = (w * 32 + l15) * S40 + l4 * 8;
    const int aoff1 = aoff0 + 16 * S40;
    const int boff  = l15 * S40 + l4 * 8;

    ushort* h1buf[2] = {h1a, h1bb};
    ushort* h2buf[2] = {h2a, h2bb};

    float creg[16];
#pragma unroll
    for (int i = 0; i < 16; i++) creg[i] = 0.f;

    const f32x4 zero4 = {0.f, 0.f, 0.f, 0.f};

    for (int t = 0; t < T_SZ; t++) {
        // ---- dependency wait (tid0 spins, block gated by barrier)
        if (tid == 0) {
            if (!z) {
                if (t >= 1) spin_ge(&flags[((t - 1) * 2 + 0) * 32 + g], 8);  // h1[t-1] data
                if (t >= 2) spin_ge(&flags[((t - 2) * 2 + 1) * 32 + g], 8);  // h1 buffer anti-dep
            } else {
                spin_ge(&flags[(t * 2 + 0) * 32 + g], 8);                    // h1[t] data
                if (t >= 1) spin_ge(&flags[((t - 1) * 2 + 1) * 32 + g], 8);  // h2[t-1] data+anti
            }
        }
        __syncthreads();

        const int Kend = z ? (t ? 512 : 256) : (t ? 256 : 0);
        const ushort* A1 = z ? h1buf[t & 1] : h1buf[(t + 1) & 1];  // z0: h1[t-1]; z1: h1[t]
        const ushort* A2 = h2buf[(t + 1) & 1];                     // z1: h2[t-1]

        f32x4 acc[2][8];
#pragma unroll
        for (int fg = 0; fg < 2; fg++)
#pragma unroll
            for (int cf = 0; cf < 8; cf++) acc[fg][cf] = zero4;

        auto loadTile = [&](int kt, short8& a0, short8& a1, short8& w0, short8& w1) {
            const ushort* Asrc; int kl;
            if (!z || kt < 256) { Asrc = A1; kl = kt; }
            else                { Asrc = A2; kl = kt - 256; }
            a0 = bp16(Asrc + (size_t)(m0 + row0) * H_SZ + kl + c40 * 8);
            a1 = bp16(Asrc + (size_t)(m0 + row1) * H_SZ + kl + c40 * 8);
            w0 = *(const short8*)(Wt + wb0 + kt);
            w1 = *(const short8*)(Wt + wb1 + kt);
        };

        short8 ga0, ga1, gw0, gw1;
        if (Kend > 0) {
            loadTile(0, ga0, ga1, gw0, gw1);
            *(short8*)(As[0] + lA0) = ga0;
            *(short8*)(As[0] + lA1) = ga1;
            *(short8*)(Ws[0] + lA0) = gw0;
            *(short8*)(Ws[0] + lA1) = gw1;
            if (Kend > 32) loadTile(32, ga0, ga1, gw0, gw1);
            __syncthreads();
        }

        int cur = 0;
        for (int kt = 0; kt < Kend; kt += 32) {
            short8 a0 = *(const short8*)(As[cur] + aoff0);
            short8 a1 = *(const short8*)(As[cur] + aoff1);
            short8 bq[8];
#pragma unroll
            for (int cf = 0; cf < 8; cf++)
                bq[cf] = *(const short8*)(Ws[cur] + boff + cf * (16 * S40));

            __builtin_amdgcn_s_setprio(1);
#pragma unroll
            for (int cf = 0; cf < 8; cf++) {
                acc[0][cf] = __builtin_amdgcn_mfma_f32_16x16x32_bf16(a0, bq[cf], acc[0][cf], 0, 0, 0);
                acc[1][cf] = __builtin_amdgcn_mfma_f32_16x16x32_bf16(a1, bq[cf], acc[1][cf], 0, 0, 0);
            }
            __builtin_amdgcn_s_setprio(0);

            if (kt + 32 < Kend) {
                *(short8*)(As[cur ^ 1] + lA0) = ga0;
                *(short8*)(As[cur ^ 1] + lA1) = ga1;
                *(short8*)(Ws[cur ^ 1] + lA0) = gw0;
                *(short8*)(Ws[cur ^ 1] + lA1) = gw1;
                if (kt + 64 < Kend) loadTile(kt + 64, ga0, ga1, gw0, gw1);
            }
            __syncthreads();
            cur ^= 1;
        }

        // ---- fused LSTM cell epilogue (c in registers). D: row=(l>>4)*4+r, col=l&15.
        // h values go to LDS (transpose), then 8B write-through stores to global.
        ushort* Hs = (ushort*)As;   // reuse: 128 rows x 32 cols, stride S40
        const bool cz = (t == 0);

#pragma unroll
        for (int fg = 0; fg < 2; fg++) {
#pragma unroll
            for (int r = 0; r < 4; r++) {
                const int lrow = w * 32 + fg * 16 + l4 * 4 + r;
                const int grow = m0 + lrow;
                const float* gb = z ? b2 : (G1 + (size_t)feat[(size_t)grow * T_SZ + t] * G4);
#pragma unroll
                for (int h16 = 0; h16 < 2; h16++) {
                    const int hcol = h0 + h16 * 16 + l15;
                    float gi = acc[fg][0 + h16][r] + gb[hcol];
                    float gj = acc[fg][2 + h16][r] + gb[256 + hcol];
                    float gf = acc[fg][4 + h16][r] + gb[512 + hcol];
                    float go = acc[fg][6 + h16][r] + gb[768 + hcol];
                    const int cidx = (fg * 4 + r) * 2 + h16;
                    float cp = cz ? 0.f : creg[cidx];
                    float cn = cp * sigm(gf + 1.f) + sigm(gi) * tanhfast(gj);
                    float hn = tanhfast(cn) * sigm(go);
                    creg[cidx] = cn;
                    Hs[lrow * S40 + h16 * 16 + l15] = f2bf(hn);
                }
            }
        }
        __syncthreads();

        // transpose-out: thread owns row=tid>>1, 16-col half=tid&1 -> 4x8B stores
        {
            ushort* hout = z ? h2buf[t & 1] : h1buf[t & 1];
            const int row = tid >> 1, ch = tid & 1;
            const ushort* src = Hs + row * S40 + ch * 16;
            u64* dst = (u64*)(hout + (size_t)(m0 + row) * H_SZ + h0 + ch * 16);
            u64 v[4];
#pragma unroll
            for (int j = 0; j < 4; j++) v[j] = *(const u64*)(src + j * 4);
#pragma unroll
            for (int j = 0; j < 4; j++)
                __hip_atomic_store(dst + j, v[j], __ATOMIC_RELAXED, __HIP_MEMORY_SCOPE_AGENT);
        }
        asm volatile("s_waitcnt vmcnt(0)" ::: "memory");
        __syncthreads();   // all waves' write-through stores complete
        if (tid == 0)
            __hip_atomic_fetch_add(&flags[(t * 2 + z) * 32 + g], 1,
                                   __ATOMIC_RELAXED, __HIP_MEMORY_SCOPE_AGENT);
    }
}

// dense+loss via MFMA: wave computes 16 rows x 80 v-cols; shfl softmax.
__global__ __launch_bounds__(256) void dense_loss(const ushort* __restrict__ h2,
                                                  const ushort* __restrict__ WdT,
                                                  const float* __restrict__ bd,
                                                  const int* __restrict__ labels,
                                                  float* __restrict__ out) {
    const int tid = threadIdx.x;
    const int w = tid >> 6, l = tid & 63;
    const int l15 = l & 15, l4 = l >> 4;
    const int m0 = blockIdx.x * 64 + w * 16;

    f32x4 acc[5];
    const f32x4 zero4 = {0.f, 0.f, 0.f, 0.f};
#pragma unroll
    for (int cf = 0; cf < 5; cf++) acc[cf] = zero4;

    for (int kt = 0; kt < 256; kt += 32) {
        short8 a = bp16(h2 + (size_t)(m0 + l15) * H_SZ + l4 * 8 + kt);
#pragma unroll
        for (int cf = 0; cf < 5; cf++) {
            short8 b = *(const short8*)(WdT + (size_t)(cf * 16 + l15) * H_SZ + l4 * 8 + kt);
            acc[cf] = __builtin_amdgcn_mfma_f32_16x16x32_bf16(a, b, acc[cf], 0, 0, 0);
        }
    }
#pragma unroll
    for (int cf = 0; cf < 5; cf++) {
        float bv = bd[cf * 16 + l15];
#pragma unroll
        for (int r = 0; r < 4; r++) acc[cf][r] += bv;
    }

#pragma unroll
    for (int r = 0; r < 4; r++) {
        const int row = m0 + l4 * 4 + r;
        float mx = acc[0][r];
#pragma unroll
        for (int cf = 1; cf < 5; cf++) mx = fmaxf(mx, acc[cf][r]);
#pragma unroll
        for (int msk = 1; msk < 16; msk <<= 1)
            mx = fmaxf(mx, __shfl_xor(mx, msk, 64));
        float s = 0.f;
#pragma unroll
        for (int cf = 0; cf < 5; cf++) s += __expf(acc[cf][r] - mx);
#pragma unroll
        for (int msk = 1; msk < 16; msk <<= 1)
            s += __shfl_xor(s, msk, 64);
        const int lab = labels[row];
        float pl = 0.f;
#pragma unroll
        for (int cf = 0; cf < 5; cf++)
            pl += (cf * 16 + l15 == lab) ? acc[cf][r] : 0.f;
#pragma unroll
        for (int msk = 1; msk < 16; msk <<= 1)
            pl += __shfl_xor(pl, msk, 64);
        if (l15 == 0)
            atomicAdd(out, (logf(s) + mx - pl) * (1.0f / B_SZ));
    }
}

extern "C" void kernel_launch(void* const* d_in, const int* in_sizes, int n_in,
                              void* d_out, int out_size, void* d_ws, size_t ws_size,
                              hipStream_t stream) {
    const int*   features = (const int*)d_in[0];
    const int*   labels   = (const int*)d_in[1];
    const float* emb      = (const float*)d_in[2];
    const float* W1       = (const float*)d_in[3];
    const float* b1       = (const float*)d_in[4];
    const float* W2       = (const float*)d_in[5];
    const float* b2       = (const float*)d_in[6];
    const float* Wd       = (const float*)d_in[7];
    const float* bd       = (const float*)d_in[8];
    float* out = (float*)d_out;

    char* base = (char*)d_ws;
    float*  G1v = (float*)base;      base += (size_t)V_SZ * G4 * 4;       // 320 KB
    ushort* h1a = (ushort*)base;     base += (size_t)B_SZ * H_SZ * 2;     // 2 MB
    ushort* h1b = (ushort*)base;     base += (size_t)B_SZ * H_SZ * 2;
    ushort* h2a = (ushort*)base;     base += (size_t)B_SZ * H_SZ * 2;
    ushort* h2b = (ushort*)base;     base += (size_t)B_SZ * H_SZ * 2;
    ushort* W1t = (ushort*)base;     base += (size_t)G4 * H_SZ * 2;       // 512 KB
    ushort* W2t = (ushort*)base;     base += (size_t)G4 * 2 * H_SZ * 2;   // 1 MB
    ushort* WdT = (ushort*)base;     base += (size_t)V_SZ * H_SZ * 2;     // 40 KB
    int*    flags = (int*)base;      base += (size_t)T_SZ * 2 * 32 * 4;   // 20 KB

    (void)hipMemsetAsync(d_out, 0, sizeof(float), stream);
    (void)hipMemsetAsync(flags, 0, (size_t)T_SZ * 2 * 32 * 4, stream);

    g1_kernel<<<(V_SZ * G4 + 255) / 256, 256, 0, stream>>>(emb, W1, b1, G1v);
    wtrans<<<(G4 * 256) / 256, 256, 0, stream>>>(W1, E_SZ, 8, W1t);
    wtrans<<<(G4 * 512) / 256, 256, 0, stream>>>(W2, 0, 9, W2t);
    wdtrans<<<(V_SZ * H_SZ + 255) / 256, 256, 0, stream>>>(Wd, WdT);

    lstm_persist<<<dim3(8, 32, 2), 256, 0, stream>>>(
        features, G1v, b2, h1a, h1b, h2a, h2b, W1t, W2t, flags, 0);

    // t=79 -> h2buf[79&1] = h2b
    dense_loss<<<B_SZ / 64, 256, 0, stream>>>(h2b, WdT, bd, labels, out);
}

// Round 8
// 1891.384 us; speedup vs baseline: 1.9172x; 1.7181x over previous
//
#include <hip/hip_runtime.h>
#include <math.h>

#define B_SZ 4096
#define T_SZ 80
#define V_SZ 80
#define E_SZ 8
#define H_SZ 256
#define G4   1024   // 4*H

typedef __attribute__((ext_vector_type(8))) short short8;
typedef __attribute__((ext_vector_type(4))) float f32x4;

typedef __attribute__((address_space(1))) const unsigned gu32;
typedef __attribute__((address_space(3))) unsigned su32;

__device__ __forceinline__ void glds16(const ushort* g, ushort* l) {
    __builtin_amdgcn_global_load_lds((gu32*)g, (su32*)l, 16, 0, 0);
}

__device__ __forceinline__ float sigm(float x) {
    return 1.f / (1.f + __expf(-x));
}
__device__ __forceinline__ float tanhfast(float x) {
    x = fminf(fmaxf(x, -15.f), 15.f);
    float t = __expf(-2.f * x);
    return (1.f - t) / (1.f + t);
}
__device__ __forceinline__ ushort f2bf(float f) {   // RNE f32->bf16
    unsigned u = __float_as_uint(f);
    u = (u + 0x7fffu + ((u >> 16) & 1u)) >> 16;
    return (ushort)u;
}

// G1[v][col] = b1[col] + sum_e emb[v][e] * W1[e][col]
__global__ __launch_bounds__(256) void g1_kernel(const float* __restrict__ emb,
                                                 const float* __restrict__ W1,
                                                 const float* __restrict__ b1,
                                                 float* __restrict__ G1) {
    int idx = blockIdx.x * 256 + threadIdx.x;
    if (idx >= V_SZ * G4) return;
    int v = idx >> 10, col = idx & 1023;
    float g = b1[col];
#pragma unroll
    for (int e = 0; e < E_SZ; e++)
        g += emb[v * E_SZ + e] * W1[e * G4 + col];
    G1[idx] = g;
}

// Fragment-ordered weight transpose.
// out[((hb*KT + ktile)*512 + c)*8 + j] = bf16(src[(k0 + ktile*32 + kq*8 + j)*1024 + ncol])
//   c = cf*64 + l;  kq=(c>>4)&3; ncol = (cf>>1)*256 + hb*32 + (cf&1)*16 + (c&15)
__global__ __launch_bounds__(256) void wtransf(const float* __restrict__ src, int k0,
                                               int KTmask, int KTsh,
                                               ushort* __restrict__ out) {
    int idx = blockIdx.x * 256 + threadIdx.x;
    int j = idx & 7;
    int c = (idx >> 3) & 511;
    int ktile = (idx >> 12) & KTmask;
    int hb = idx >> (12 + KTsh);
    int cf = c >> 6;
    int k = k0 + ktile * 32 + ((c >> 4) & 3) * 8 + j;
    int ncol = (cf >> 1) * 256 + hb * 32 + (cf & 1) * 16 + (c & 15);
    out[idx] = f2bf(src[(size_t)k * G4 + ncol]);
}

// WdT[v][h] = bf16(Wd[h*V + v])
__global__ __launch_bounds__(256) void wdtrans(const float* __restrict__ src,
                                               ushort* __restrict__ out) {
    int idx = blockIdx.x * 256 + threadIdx.x;
    if (idx >= V_SZ * H_SZ) return;
    int v = idx >> 8, h = idx & 255;
    out[idx] = f2bf(src[h * V_SZ + v]);
}

// Fused step: blockIdx.z==0 -> layer1(t); z==1 -> layer2(t-1)  (skewed pipeline).
// Block = 128 rows x (4 gates x 32 hcols); 4 waves, wave w owns rows w*32..w*32+31.
// LDS is fragment-linear: chunk c at offset c*16B; reads are base+lane*16B -> 0 conflicts.
// Staging via global_load_lds: W source is fragment-ordered global (linear);
// A source is per-lane pre-swizzled from row-major h.
__global__ __launch_bounds__(256) void lstm_fused(
    const ushort* __restrict__ A1h, int Kend1,
    const int*   __restrict__ feat,   // features + t
    const float* __restrict__ G1,
    float* __restrict__ c1, ushort* __restrict__ h1out,
    const ushort* __restrict__ A2x, const ushort* __restrict__ A2h, int Kend2,
    const float* __restrict__ b2,
    float* __restrict__ c2, ushort* __restrict__ h2out,
    const ushort* __restrict__ W1f, const ushort* __restrict__ W2f) {

    const int z = blockIdx.z;
    const int Kend = z ? Kend2 : Kend1;
    if (Kend < 0) return;
    const int KT = z ? 16 : 8;                 // K/32
    const ushort* __restrict__ Wf = z ? W2f : W1f;

    __shared__ __align__(16) ushort As[2][4096];   // 512 chunks x 16B
    __shared__ __align__(16) ushort Ws[2][4096];

    const int tid = threadIdx.x;
    const int w = tid >> 6, l = tid & 63;
    const int l15 = l & 15, l4 = l >> 4;
    const int m0 = blockIdx.y * 128;
    const int hb = blockIdx.x;                 // h-block
    const int h0 = hb * 32;

    // staging: wave tw stages chunk-blocks S0=tw*2, S1=tw*2+1 (64 chunks each)
    // A chunk c: row=(c>>7)*32+((c>>6)&1)*16+(c&15), kq=(c>>4)&3
    const int rowS0 = w * 32 + l15;            // S0: fg=0
    const int rowS1 = w * 32 + 16 + l15;       // S1: fg=1
    const int kq8 = l4 * 8;
    const int S0 = w * 2, S1 = w * 2 + 1;
    const size_t wtileb = (size_t)hb * KT * 512;   // W fragment base for this h-block

    // fragment read offsets (shorts)
    const int aoff0 = (w * 128 + l) * 8;           // chunk (w*2+0)*64 + l
    const int aoff1 = (w * 128 + 64 + l) * 8;      // chunk (w*2+1)*64 + l
    const int boff  = l * 8;                        // chunk cf*64 + l  (+cf*512)

    f32x4 acc[2][8];
    const f32x4 zero4 = {0.f, 0.f, 0.f, 0.f};
#pragma unroll
    for (int fg = 0; fg < 2; fg++)
#pragma unroll
        for (int cf = 0; cf < 8; cf++) acc[fg][cf] = zero4;

    auto stage = [&](int buf, int kt) {
        const ushort* Asrc; int kl;
        if (!z || kt < 256) { Asrc = z ? A2x : A1h; kl = kt; }
        else                { Asrc = A2h; kl = kt - 256; }
        // A: per-lane pre-swizzled source, linear LDS dest
        glds16(Asrc + (size_t)(m0 + rowS0) * H_SZ + kl + kq8, As[buf] + S0 * 512);
        glds16(Asrc + (size_t)(m0 + rowS1) * H_SZ + kl + kq8, As[buf] + S1 * 512);
        // W: fragment-ordered global, fully linear
        const ushort* wsrc = Wf + (wtileb + (size_t)(kt >> 5) * 512) * 8;
        glds16(wsrc + (S0 * 64 + l) * 8, Ws[buf] + S0 * 512);
        glds16(wsrc + (S1 * 64 + l) * 8, Ws[buf] + S1 * 512);
    };

    if (Kend > 0) {
        stage(0, 0);
        __syncthreads();
        int cur = 0;
        for (int kt = 0; kt < Kend; kt += 32) {
            if (kt + 32 < Kend) stage(cur ^ 1, kt + 32);

            short8 a0 = *(const short8*)(As[cur] + aoff0);
            short8 a1 = *(const short8*)(As[cur] + aoff1);
            short8 bq[8];
#pragma unroll
            for (int cf = 0; cf < 8; cf++)
                bq[cf] = *(const short8*)(Ws[cur] + cf * 512 + boff);

            __builtin_amdgcn_s_setprio(1);
#pragma unroll
            for (int cf = 0; cf < 8; cf++) {
                acc[0][cf] = __builtin_amdgcn_mfma_f32_16x16x32_bf16(a0, bq[cf], acc[0][cf], 0, 0, 0);
                acc[1][cf] = __builtin_amdgcn_mfma_f32_16x16x32_bf16(a1, bq[cf], acc[1][cf], 0, 0, 0);
            }
            __builtin_amdgcn_s_setprio(0);
            __syncthreads();
            cur ^= 1;
        }
    }

    // fused LSTM cell epilogue. D layout: row=(l>>4)*4+r, col=l&15.
    float* __restrict__ cbuf = z ? c2 : c1;
    ushort* __restrict__ hout = z ? h2out : h1out;
    const bool cz = z ? (Kend == 256) : (Kend == 0);

#pragma unroll
    for (int fg = 0; fg < 2; fg++) {
#pragma unroll
        for (int r = 0; r < 4; r++) {
            const int grow = m0 + w * 32 + fg * 16 + l4 * 4 + r;
            const float* gb = z ? b2 : (G1 + (size_t)feat[(size_t)grow * T_SZ] * G4);
#pragma unroll
            for (int h16 = 0; h16 < 2; h16++) {
                const int hcol = h0 + h16 * 16 + l15;
                float gi = acc[fg][0 + h16][r] + gb[hcol];
                float gj = acc[fg][2 + h16][r] + gb[256 + hcol];
                float gf = acc[fg][4 + h16][r] + gb[512 + hcol];
                float go = acc[fg][6 + h16][r] + gb[768 + hcol];
                const size_t ci = (size_t)grow * H_SZ + hcol;
                float cp = cz ? 0.f : cbuf[ci];
                float cn = cp * sigm(gf + 1.f) + sigm(gi) * tanhfast(gj);
                float hn = tanhfast(cn) * sigm(go);
                cbuf[ci] = cn;
                hout[ci] = f2bf(hn);
            }
        }
    }
}

// dense+loss via MFMA: wave computes 16 rows x 80 v-cols; shfl softmax.
__global__ __launch_bounds__(256) void dense_loss(const ushort* __restrict__ h2,
                                                  const ushort* __restrict__ WdT,
                                                  const float* __restrict__ bd,
                                                  const int* __restrict__ labels,
                                                  float* __restrict__ out) {
    const int tid = threadIdx.x;
    const int w = tid >> 6, l = tid & 63;
    const int l15 = l & 15, l4 = l >> 4;
    const int m0 = blockIdx.x * 64 + w * 16;

    f32x4 acc[5];
    const f32x4 zero4 = {0.f, 0.f, 0.f, 0.f};
#pragma unroll
    for (int cf = 0; cf < 5; cf++) acc[cf] = zero4;

    for (int kt = 0; kt < 256; kt += 32) {
        short8 a = *(const short8*)(h2 + (size_t)(m0 + l15) * H_SZ + l4 * 8 + kt);
#pragma unroll
        for (int cf = 0; cf < 5; cf++) {
            short8 b = *(const short8*)(WdT + (size_t)(cf * 16 + l15) * H_SZ + l4 * 8 + kt);
            acc[cf] = __builtin_amdgcn_mfma_f32_16x16x32_bf16(a, b, acc[cf], 0, 0, 0);
        }
    }
#pragma unroll
    for (int cf = 0; cf < 5; cf++) {
        float bv = bd[cf * 16 + l15];
#pragma unroll
        for (int r = 0; r < 4; r++) acc[cf][r] += bv;
    }

#pragma unroll
    for (int r = 0; r < 4; r++) {
        const int row = m0 + l4 * 4 + r;
        float mx = acc[0][r];
#pragma unroll
        for (int cf = 1; cf < 5; cf++) mx = fmaxf(mx, acc[cf][r]);
#pragma unroll
        for (int msk = 1; msk < 16; msk <<= 1)
            mx = fmaxf(mx, __shfl_xor(mx, msk, 64));
        float s = 0.f;
#pragma unroll
        for (int cf = 0; cf < 5; cf++) s += __expf(acc[cf][r] - mx);
#pragma unroll
        for (int msk = 1; msk < 16; msk <<= 1)
            s += __shfl_xor(s, msk, 64);
        const int lab = labels[row];
        float pl = 0.f;
#pragma unroll
        for (int cf = 0; cf < 5; cf++)
            pl += (cf * 16 + l15 == lab) ? acc[cf][r] : 0.f;
#pragma unroll
        for (int msk = 1; msk < 16; msk <<= 1)
            pl += __shfl_xor(pl, msk, 64);
        if (l15 == 0)
            atomicAdd(out, (logf(s) + mx - pl) * (1.0f / B_SZ));
    }
}

extern "C" void kernel_launch(void* const* d_in, const int* in_sizes, int n_in,
                              void* d_out, int out_size, void* d_ws, size_t ws_size,
                              hipStream_t stream) {
    const int*   features = (const int*)d_in[0];
    const int*   labels   = (const int*)d_in[1];
    const float* emb      = (const float*)d_in[2];
    const float* W1       = (const float*)d_in[3];
    const float* b1       = (const float*)d_in[4];
    const float* W2       = (const float*)d_in[5];
    const float* b2       = (const float*)d_in[6];
    const float* Wd       = (const float*)d_in[7];
    const float* bd       = (const float*)d_in[8];
    float* out = (float*)d_out;

    char* base = (char*)d_ws;
    float*  G1v = (float*)base;      base += (size_t)V_SZ * G4 * 4;            // 320 KB
    float*  c1  = (float*)base;      base += (size_t)B_SZ * H_SZ * 4;          // 4 MB
    float*  c2  = (float*)base;      base += (size_t)B_SZ * H_SZ * 4;          // 4 MB
    ushort* h1b[2]; ushort* h2b[2];
    h1b[0] = (ushort*)base;          base += (size_t)B_SZ * H_SZ * 2;
    h1b[1] = (ushort*)base;          base += (size_t)B_SZ * H_SZ * 2;
    h2b[0] = (ushort*)base;          base += (size_t)B_SZ * H_SZ * 2;
    h2b[1] = (ushort*)base;          base += (size_t)B_SZ * H_SZ * 2;
    ushort* W1f = (ushort*)base;     base += (size_t)8 * 8 * 512 * 8 * 2;      // 512 KB
    ushort* W2f = (ushort*)base;     base += (size_t)8 * 16 * 512 * 8 * 2;     // 1 MB
    ushort* WdT = (ushort*)base;     base += (size_t)V_SZ * H_SZ * 2;          // 40 KB

    (void)hipMemsetAsync(d_out, 0, sizeof(float), stream);
    g1_kernel<<<(V_SZ * G4 + 255) / 256, 256, 0, stream>>>(emb, W1, b1, G1v);
    wtransf<<<(8 * 8 * 512 * 8) / 256, 256, 0, stream>>>(W1, E_SZ, 7, 3, W1f);
    wtransf<<<(8 * 16 * 512 * 8) / 256, 256, 0, stream>>>(W2, 0, 15, 4, W2f);
    wdtrans<<<(V_SZ * H_SZ + 255) / 256, 256, 0, stream>>>(Wd, WdT);

    dim3 grid(H_SZ / 32, B_SZ / 128, 2), blk(256);
    for (int t = 0; t <= T_SZ; t++) {
        const int Kend1 = (t < T_SZ) ? (t ? 256 : 0) : -1;
        const int Kend2 = (t >= 1) ? ((t >= 2) ? 512 : 256) : -1;
        lstm_fused<<<grid, blk, 0, stream>>>(
            (t && t < T_SZ) ? h1b[(t - 1) & 1] : nullptr, Kend1,
            features + t, G1v, c1, h1b[t & 1],
            (t >= 1) ? h1b[(t - 1) & 1] : nullptr,
            (t >= 2) ? h2b[(t - 2) & 1] : nullptr, Kend2,
            b2, c2, (t >= 1) ? h2b[(t - 1) & 1] : nullptr,
            W1f, W2f);
    }
    dense_loss<<<B_SZ / 64, 256, 0, stream>>>(h2b[(T_SZ - 1) & 1], WdT, bd, labels, out);
}

// Round 9
// 1632.264 us; speedup vs baseline: 2.2216x; 1.1587x over previous
//
#include <hip/hip_runtime.h>
#include <math.h>

#define B_SZ 4096
#define T_SZ 80
#define V_SZ 80
#define E_SZ 8
#define H_SZ 256
#define G4   1024   // 4*H

typedef __attribute__((ext_vector_type(8))) short short8;
typedef __attribute__((ext_vector_type(4))) float f32x4;

typedef __attribute__((address_space(1))) const unsigned gu32;
typedef __attribute__((address_space(3))) unsigned su32;

__device__ __forceinline__ void glds16(const ushort* g, ushort* l) {
    __builtin_amdgcn_global_load_lds((gu32*)g, (su32*)l, 16, 0, 0);
}

__device__ __forceinline__ float sigm(float x) {
    return 1.f / (1.f + __expf(-x));
}
__device__ __forceinline__ float tanhfast(float x) {
    x = fminf(fmaxf(x, -15.f), 15.f);
    float t = __expf(-2.f * x);
    return (1.f - t) / (1.f + t);
}
__device__ __forceinline__ ushort f2bf(float f) {   // RNE f32->bf16
    unsigned u = __float_as_uint(f);
    u = (u + 0x7fffu + ((u >> 16) & 1u)) >> 16;
    return (ushort)u;
}

// G1[v][col] = b1[col] + sum_e emb[v][e] * W1[e][col]
__global__ __launch_bounds__(256) void g1_kernel(const float* __restrict__ emb,
                                                 const float* __restrict__ W1,
                                                 const float* __restrict__ b1,
                                                 float* __restrict__ G1) {
    int idx = blockIdx.x * 256 + threadIdx.x;
    if (idx >= V_SZ * G4) return;
    int v = idx >> 10, col = idx & 1023;
    float g = b1[col];
#pragma unroll
    for (int e = 0; e < E_SZ; e++)
        g += emb[v * E_SZ + e] * W1[e * G4 + col];
    G1[idx] = g;
}

// Fragment-ordered weight transpose.
// out[((hb*KT + ktile)*512 + c)*8 + j] = bf16(src[(k0 + ktile*32 + kq*8 + j)*1024 + ncol])
//   c = cf*64 + l;  kq=(c>>4)&3; ncol = (cf>>1)*256 + hb*32 + (cf&1)*16 + (c&15)
__global__ __launch_bounds__(256) void wtransf(const float* __restrict__ src, int k0,
                                               int KTmask, int KTsh,
                                               ushort* __restrict__ out) {
    int idx = blockIdx.x * 256 + threadIdx.x;
    int j = idx & 7;
    int c = (idx >> 3) & 511;
    int ktile = (idx >> 12) & KTmask;
    int hb = idx >> (12 + KTsh);
    int cf = c >> 6;
    int k = k0 + ktile * 32 + ((c >> 4) & 3) * 8 + j;
    int ncol = (cf >> 1) * 256 + hb * 32 + (cf & 1) * 16 + (c & 15);
    out[idx] = f2bf(src[(size_t)k * G4 + ncol]);
}

// WdT[v][h] = bf16(Wd[h*V + v])
__global__ __launch_bounds__(256) void wdtrans(const float* __restrict__ src,
                                               ushort* __restrict__ out) {
    int idx = blockIdx.x * 256 + threadIdx.x;
    if (idx >= V_SZ * H_SZ) return;
    int v = idx >> 8, h = idx & 255;
    out[idx] = f2bf(src[h * V_SZ + v]);
}

// Fused step: blockIdx.z==0 -> layer1(t); z==1 -> layer2(t-1)  (skewed pipeline).
// Grid (m-group, h-block, z): all consumers of one A-slice share an XCD, and the
// h1 producer (z=0) / consumer (z=1) pair shares an XCD (ids differ by 256).
// Block = 128 rows x (4 gates x 32 hcols); 4 waves, wave w owns rows w*32..w*32+31.
// LDS is fragment-linear: chunk c at offset c*16B; reads are base+lane*16B -> 0 conflicts.
__global__ __launch_bounds__(256) void lstm_fused(
    const ushort* __restrict__ A1h, int Kend1,
    const int*   __restrict__ feat,   // features + t
    const float* __restrict__ G1,
    float* __restrict__ c1, ushort* __restrict__ h1out,
    const ushort* __restrict__ A2x, const ushort* __restrict__ A2h, int Kend2,
    const float* __restrict__ b2,
    float* __restrict__ c2, ushort* __restrict__ h2out,
    const ushort* __restrict__ W1f, const ushort* __restrict__ W2f) {

    const int z = blockIdx.z;
    const int Kend = z ? Kend2 : Kend1;
    if (Kend < 0) return;
    const int KT = z ? 16 : 8;                 // K/32
    const ushort* __restrict__ Wf = z ? W2f : W1f;

    __shared__ __align__(16) ushort As[2][4096];   // 512 chunks x 16B
    __shared__ __align__(16) ushort Ws[2][4096];

    const int tid = threadIdx.x;
    const int w = tid >> 6, l = tid & 63;
    const int l15 = l & 15, l4 = l >> 4;
    const int m0 = blockIdx.x * 128;
    const int hb = blockIdx.y;                 // h-block
    const int h0 = hb * 32;

    // staging: wave tw stages chunk-blocks S0=tw*2, S1=tw*2+1 (64 chunks each)
    const int rowS0 = w * 32 + l15;            // S0: fg=0
    const int rowS1 = w * 32 + 16 + l15;       // S1: fg=1
    const int kq8 = l4 * 8;
    const int S0 = w * 2, S1 = w * 2 + 1;
    const size_t wtileb = (size_t)hb * KT * 512;   // W fragment base for this h-block

    // fragment read offsets (shorts)
    const int aoff0 = (w * 128 + l) * 8;           // chunk (w*2+0)*64 + l
    const int aoff1 = (w * 128 + 64 + l) * 8;      // chunk (w*2+1)*64 + l
    const int boff  = l * 8;                        // chunk cf*64 + l  (+cf*512)

    f32x4 acc[2][8];
    const f32x4 zero4 = {0.f, 0.f, 0.f, 0.f};
#pragma unroll
    for (int fg = 0; fg < 2; fg++)
#pragma unroll
        for (int cf = 0; cf < 8; cf++) acc[fg][cf] = zero4;

    auto stage = [&](int buf, int kt) {
        const ushort* Asrc; int kl;
        if (!z || kt < 256) { Asrc = z ? A2x : A1h; kl = kt; }
        else                { Asrc = A2h; kl = kt - 256; }
        // A: per-lane pre-swizzled source, linear LDS dest
        glds16(Asrc + (size_t)(m0 + rowS0) * H_SZ + kl + kq8, As[buf] + S0 * 512);
        glds16(Asrc + (size_t)(m0 + rowS1) * H_SZ + kl + kq8, As[buf] + S1 * 512);
        // W: fragment-ordered global, fully linear
        const ushort* wsrc = Wf + (wtileb + (size_t)(kt >> 5) * 512) * 8;
        glds16(wsrc + (S0 * 64 + l) * 8, Ws[buf] + S0 * 512);
        glds16(wsrc + (S1 * 64 + l) * 8, Ws[buf] + S1 * 512);
    };

    if (Kend > 0) {
        stage(0, 0);
        __syncthreads();
        int cur = 0;
        for (int kt = 0; kt < Kend; kt += 32) {
            // 1) ds-load fragments for this tile
            short8 a0 = *(const short8*)(As[cur] + aoff0);
            short8 a1 = *(const short8*)(As[cur] + aoff1);
            short8 bq[8];
#pragma unroll
            for (int cf = 0; cf < 8; cf++)
                bq[cf] = *(const short8*)(Ws[cur] + cf * 512 + boff);

            // 2) issue async prefetch of next tile into other buffer
            if (kt + 32 < Kend) stage(cur ^ 1, kt + 32);

            // 3) MFMA cluster
            __builtin_amdgcn_s_setprio(1);
#pragma unroll
            for (int cf = 0; cf < 8; cf++) {
                acc[0][cf] = __builtin_amdgcn_mfma_f32_16x16x32_bf16(a0, bq[cf], acc[0][cf], 0, 0, 0);
                acc[1][cf] = __builtin_amdgcn_mfma_f32_16x16x32_bf16(a1, bq[cf], acc[1][cf], 0, 0, 0);
            }
            __builtin_amdgcn_s_setprio(0);
            __syncthreads();
            cur ^= 1;
        }
    }

    // fused LSTM cell epilogue. D layout: row=(l>>4)*4+r, col=l&15.
    float* __restrict__ cbuf = z ? c2 : c1;
    ushort* __restrict__ hout = z ? h2out : h1out;
    const bool cz = z ? (Kend == 256) : (Kend == 0);

#pragma unroll
    for (int fg = 0; fg < 2; fg++) {
#pragma unroll
        for (int r = 0; r < 4; r++) {
            const int grow = m0 + w * 32 + fg * 16 + l4 * 4 + r;
            const float* gb = z ? b2 : (G1 + (size_t)feat[(size_t)grow * T_SZ] * G4);
#pragma unroll
            for (int h16 = 0; h16 < 2; h16++) {
                const int hcol = h0 + h16 * 16 + l15;
                float gi = acc[fg][0 + h16][r] + gb[hcol];
                float gj = acc[fg][2 + h16][r] + gb[256 + hcol];
                float gf = acc[fg][4 + h16][r] + gb[512 + hcol];
                float go = acc[fg][6 + h16][r] + gb[768 + hcol];
                const size_t ci = (size_t)grow * H_SZ + hcol;
                float cp = cz ? 0.f : cbuf[ci];
                float cn = cp * sigm(gf + 1.f) + sigm(gi) * tanhfast(gj);
                float hn = tanhfast(cn) * sigm(go);
                cbuf[ci] = cn;
                hout[ci] = f2bf(hn);
            }
        }
    }
}

// dense+loss via MFMA: wave computes 16 rows x 80 v-cols; shfl softmax.
__global__ __launch_bounds__(256) void dense_loss(const ushort* __restrict__ h2,
                                                  const ushort* __restrict__ WdT,
                                                  const float* __restrict__ bd,
                                                  const int* __restrict__ labels,
                                                  float* __restrict__ out) {
    const int tid = threadIdx.x;
    const int w = tid >> 6, l = tid & 63;
    const int l15 = l & 15, l4 = l >> 4;
    const int m0 = blockIdx.x * 64 + w * 16;

    f32x4 acc[5];
    const f32x4 zero4 = {0.f, 0.f, 0.f, 0.f};
#pragma unroll
    for (int cf = 0; cf < 5; cf++) acc[cf] = zero4;

    for (int kt = 0; kt < 256; kt += 32) {
        short8 a = *(const short8*)(h2 + (size_t)(m0 + l15) * H_SZ + l4 * 8 + kt);
#pragma unroll
        for (int cf = 0; cf < 5; cf++) {
            short8 b = *(const short8*)(WdT + (size_t)(cf * 16 + l15) * H_SZ + l4 * 8 + kt);
            acc[cf] = __builtin_amdgcn_mfma_f32_16x16x32_bf16(a, b, acc[cf], 0, 0, 0);
        }
    }
#pragma unroll
    for (int cf = 0; cf < 5; cf++) {
        float bv = bd[cf * 16 + l15];
#pragma unroll
        for (int r = 0; r < 4; r++) acc[cf][r] += bv;
    }

#pragma unroll
    for (int r = 0; r < 4; r++) {
        const int row = m0 + l4 * 4 + r;
        float mx = acc[0][r];
#pragma unroll
        for (int cf = 1; cf < 5; cf++) mx = fmaxf(mx, acc[cf][r]);
#pragma unroll
        for (int msk = 1; msk < 16; msk <<= 1)
            mx = fmaxf(mx, __shfl_xor(mx, msk, 64));
        float s = 0.f;
#pragma unroll
        for (int cf = 0; cf < 5; cf++) s += __expf(acc[cf][r] - mx);
#pragma unroll
        for (int msk = 1; msk < 16; msk <<= 1)
            s += __shfl_xor(s, msk, 64);
        const int lab = labels[row];
        float pl = 0.f;
#pragma unroll
        for (int cf = 0; cf < 5; cf++)
            pl += (cf * 16 + l15 == lab) ? acc[cf][r] : 0.f;
#pragma unroll
        for (int msk = 1; msk < 16; msk <<= 1)
            pl += __shfl_xor(pl, msk, 64);
        if (l15 == 0)
            atomicAdd(out, (logf(s) + mx - pl) * (1.0f / B_SZ));
    }
}

extern "C" void kernel_launch(void* const* d_in, const int* in_sizes, int n_in,
                              void* d_out, int out_size, void* d_ws, size_t ws_size,
                              hipStream_t stream) {
    const int*   features = (const int*)d_in[0];
    const int*   labels   = (const int*)d_in[1];
    const float* emb      = (const float*)d_in[2];
    const float* W1       = (const float*)d_in[3];
    const float* b1       = (const float*)d_in[4];
    const float* W2       = (const float*)d_in[5];
    const float* b2       = (const float*)d_in[6];
    const float* Wd       = (const float*)d_in[7];
    const float* bd       = (const float*)d_in[8];
    float* out = (float*)d_out;

    char* base = (char*)d_ws;
    float*  G1v = (float*)base;      base += (size_t)V_SZ * G4 * 4;            // 320 KB
    float*  c1  = (float*)base;      base += (size_t)B_SZ * H_SZ * 4;          // 4 MB
    float*  c2  = (float*)base;      base += (size_t)B_SZ * H_SZ * 4;          // 4 MB
    ushort* h1b[2]; ushort* h2b[2];
    h1b[0] = (ushort*)base;          base += (size_t)B_SZ * H_SZ * 2;
    h1b[1] = (ushort*)base;          base += (size_t)B_SZ * H_SZ * 2;
    h2b[0] = (ushort*)base;          base += (size_t)B_SZ * H_SZ * 2;
    h2b[1] = (ushort*)base;          base += (size_t)B_SZ * H_SZ * 2;
    ushort* W1f = (ushort*)base;     base += (size_t)8 * 8 * 512 * 8 * 2;      // 512 KB
    ushort* W2f = (ushort*)base;     base += (size_t)8 * 16 * 512 * 8 * 2;     // 1 MB
    ushort* WdT = (ushort*)base;     base += (size_t)V_SZ * H_SZ * 2;          // 40 KB

    (void)hipMemsetAsync(d_out, 0, sizeof(float), stream);
    g1_kernel<<<(V_SZ * G4 + 255) / 256, 256, 0, stream>>>(emb, W1, b1, G1v);
    wtransf<<<(8 * 8 * 512 * 8) / 256, 256, 0, stream>>>(W1, E_SZ, 7, 3, W1f);
    wtransf<<<(8 * 16 * 512 * 8) / 256, 256, 0, stream>>>(W2, 0, 15, 4, W2f);
    wdtrans<<<(V_SZ * H_SZ + 255) / 256, 256, 0, stream>>>(Wd, WdT);

    dim3 grid(B_SZ / 128, H_SZ / 32, 2), blk(256);
    for (int t = 0; t <= T_SZ; t++) {
        const int Kend1 = (t < T_SZ) ? (t ? 256 : 0) : -1;
        const int Kend2 = (t >= 1) ? ((t >= 2) ? 512 : 256) : -1;
        lstm_fused<<<grid, blk, 0, stream>>>(
            (t && t < T_SZ) ? h1b[(t - 1) & 1] : nullptr, Kend1,
            features + t, G1v, c1, h1b[t & 1],
            (t >= 1) ? h1b[(t - 1) & 1] : nullptr,
            (t >= 2) ? h2b[(t - 2) & 1] : nullptr, Kend2,
            b2, c2, (t >= 1) ? h2b[(t - 1) & 1] : nullptr,
            W1f, W2f);
    }
    dense_loss<<<B_SZ / 64, 256, 0, stream>>>(h2b[(T_SZ - 1) & 1], WdT, bd, labels, out);
}